// Round 9
// baseline (258.148 us; speedup 1.0000x reference)
//
#include <hip/hip_runtime.h>
#include <math.h>

// GAT 2-layer: N=10000, E=160000 (+N self loops), IN=128, H1=8, C1=128, OUT=64.
// R9: wave-per-node aggregation (no barriers), shuffle-scan, merged prep.
//     GEMMs stay bf16 MFMA (16x16x32, fp32 accumulate) from R8.

#define NEG_SLOPE 0.2f

typedef short bf16x8 __attribute__((ext_vector_type(8)));
typedef float f32x4 __attribute__((ext_vector_type(4)));

__device__ __forceinline__ float leaky(float v) { return v >= 0.0f ? v : NEG_SLOPE * v; }

__device__ __forceinline__ unsigned short f2bf(float f) {
    unsigned u = __float_as_uint(f);
    u += 0x7FFFu + ((u >> 16) & 1u);   // round-to-nearest-even
    return (unsigned short)(u >> 16);
}

// ---------------- CSR build ----------------

__global__ void count_kernel(const int* __restrict__ ei, int* __restrict__ counts, int E, int N) {
    int i = blockIdx.x * blockDim.x + threadIdx.x;
    int M = E + N;
    if (i >= M) return;
    int dst = (i < E) ? ei[E + i] : (i - E);   // self-loop tail
    atomicAdd(&counts[dst], 1);
}

// single-block scan: serial per-thread sums + wave shuffle scan (2 barriers)
__global__ __launch_bounds__(1024) void scan_kernel(
    const int* __restrict__ counts, int* __restrict__ offsets,
    int* __restrict__ cursor, int N) {
    __shared__ int wsum[16];
    int t = threadIdx.x;
    int per = (N + 1023) / 1024;
    int base = t * per;
    int s = 0;
    for (int j = 0; j < per; j++) {
        int idx = base + j;
        if (idx < N) s += counts[idx];
    }
    int lane = t & 63, wid = t >> 6;
    int inc = s;
#pragma unroll
    for (int off = 1; off <= 32; off <<= 1) {
        int v = __shfl_up(inc, off);
        if (lane >= off) inc += v;
    }
    if (lane == 63) wsum[wid] = inc;
    __syncthreads();
    if (t < 16) {
        int v = wsum[t];
        int iv = v;
#pragma unroll
        for (int off = 1; off <= 8; off <<= 1) {
            int u = __shfl_up(iv, off);
            if (t >= off) iv += u;
        }
        wsum[t] = iv - v;   // exclusive
    }
    __syncthreads();
    int run = wsum[wid] + inc - s;   // exclusive prefix for this thread's chunk
    for (int j = 0; j < per; j++) {
        int idx = base + j;
        if (idx < N) {
            offsets[idx] = run;
            cursor[idx] = run;
            run += counts[idx];
        }
    }
    if (t == 1023) offsets[N] = run;
}

__global__ void fill_kernel(const int* __restrict__ ei, int* __restrict__ cursor,
                            int* __restrict__ srcs, int E, int N) {
    int i = blockIdx.x * blockDim.x + threadIdx.x;
    int M = E + N;
    if (i >= M) return;
    int src, dst;
    if (i < E) { src = ei[i]; dst = ei[E + i]; }
    else       { src = dst = i - E; }
    int pos = atomicAdd(&cursor[dst], 1);
    srcs[pos] = src;
}

// ---------------- prep_all: As/Ad + W1->W1bT [h][c][k] bf16 + W2->W2bT [c][k] bf16 ---

__global__ __launch_bounds__(256) void prep_all(
    const float* __restrict__ W1, const float* __restrict__ a_src1,
    const float* __restrict__ a_dst1, const float* __restrict__ W2,
    float* __restrict__ As, float* __restrict__ Ad,
    unsigned short* __restrict__ W1bT, unsigned short* __restrict__ W2bT) {
    int b = blockIdx.x;
    __shared__ unsigned short tile[32][33];
    if (b < 4) {
        int i = b * 256 + threadIdx.x;   // 0..1023
        int k = i >> 3, h = i & 7;
        float ss = 0.f, sd = 0.f;
        for (int c = 0; c < 128; c += 4) {
            float4 w = *(const float4*)(W1 + (size_t)k * 1024 + h * 128 + c);
            float4 a = *(const float4*)(a_src1 + h * 128 + c);
            float4 d = *(const float4*)(a_dst1 + h * 128 + c);
            ss += w.x * a.x + w.y * a.y + w.z * a.z + w.w * a.w;
            sd += w.x * d.x + w.y * d.y + w.z * d.z + w.w * d.w;
        }
        As[k * 8 + h] = ss;
        Ad[k * 8 + h] = sd;
    } else if (b < 132) {
        int bb = b - 4;
        int kt = bb & 3, hct = bb >> 2;
        int j = threadIdx.x & 31;
        int i0 = threadIdx.x >> 5;
        for (int i = i0; i < 32; i += 8)
            tile[i][j] = f2bf(W1[(size_t)(kt * 32 + i) * 1024 + hct * 32 + j]);
        __syncthreads();
        for (int i = i0; i < 32; i += 8) {
            int hc = hct * 32 + i, k = kt * 32 + j;
            int h = hc >> 7, c = hc & 127;
            W1bT[h * 16384 + c * 128 + k] = tile[j][i];
        }
    } else {
        int bb = b - 132;
        int kt = bb & 31, ctile = bb >> 5;
        int j = threadIdx.x & 31;
        int i0 = threadIdx.x >> 5;
        for (int i = i0; i < 32; i += 8)
            tile[i][j] = f2bf(W2[(size_t)(kt * 32 + i) * 64 + ctile * 32 + j]);
        __syncthreads();
        for (int i = i0; i < 32; i += 8)
            W2bT[(size_t)(ctile * 32 + i) * 1024 + kt * 32 + j] = tile[j][i];
    }
}

// ---------------- alpha1: as1/ad1 = x @ As / Ad  [N,8] ----------------

__global__ __launch_bounds__(256) void alpha1_kernel(
    const float* __restrict__ x, const float* __restrict__ As, const float* __restrict__ Ad,
    float* __restrict__ as1, float* __restrict__ ad1, int N) {
    __shared__ float sAs[1024], sAd[1024];
    int t = threadIdx.x;
    {
        int i = t * 4;
        *(float4*)(sAs + i) = *(const float4*)(As + i);
        *(float4*)(sAd + i) = *(const float4*)(Ad + i);
    }
    __syncthreads();
    int node = blockIdx.x * 32 + (t >> 3);
    int h = t & 7;
    if (node >= N) return;
    float accs = 0.f, accd = 0.f;
    for (int k = 0; k < 128; k += 4) {
        float4 xv = *(const float4*)(x + (size_t)node * 128 + k);
        accs += xv.x * sAs[k * 8 + h] + xv.y * sAs[(k + 1) * 8 + h]
              + xv.z * sAs[(k + 2) * 8 + h] + xv.w * sAs[(k + 3) * 8 + h];
        accd += xv.x * sAd[k * 8 + h] + xv.y * sAd[(k + 1) * 8 + h]
              + xv.z * sAd[(k + 2) * 8 + h] + xv.w * sAd[(k + 3) * 8 + h];
    }
    as1[node * 8 + h] = accs;
    ad1[node * 8 + h] = accd;
}

// ---------------- l1_aggx: wave-per-node, y_b[n,h,:] bf16 --------------------
// Weight-phase lane map: e8=lane>>3 (edge slot), hw=lane&7 (head).
// Acc lane map: ha=lane>>3 (head), cg=lane&7 -> channels cg*16..+15 of head ha.
// No __syncthreads anywhere.

__global__ __launch_bounds__(256) void l1_aggx(
    const float* __restrict__ x, const float* __restrict__ as1, const float* __restrict__ ad1,
    const int* __restrict__ offsets, const int* __restrict__ srcs,
    unsigned short* __restrict__ y_b, int N) {
    int n = blockIdx.x * 4 + (threadIdx.x >> 6);
    if (n >= N) return;
    int lane = threadIdx.x & 63;
    int e8 = lane >> 3, hw = lane & 7;
    int beg = offsets[n];
    int deg = offsets[n + 1] - beg;
    float adv = ad1[n * 8 + hw];
    // per-head max
    float m = -3.4e38f;
    for (int g = 0; g * 8 < deg; g++) {
        int i = g * 8 + e8;
        if (i < deg) {
            int s = srcs[beg + i];
            m = fmaxf(m, leaky(as1[s * 8 + hw] + adv));
        }
    }
    m = fmaxf(m, __shfl_xor(m, 8));
    m = fmaxf(m, __shfl_xor(m, 16));
    m = fmaxf(m, __shfl_xor(m, 32));
    // accumulate
    int ha = lane >> 3, cg = lane & 7;
    float acc[16];
#pragma unroll
    for (int q = 0; q < 16; q++) acc[q] = 0.f;
    float wsum = 0.f;
    for (int g = 0; g * 8 < deg; g++) {
        int i = g * 8 + e8;
        int s = 0;
        float w = 0.f;
        if (i < deg) {
            s = srcs[beg + i];
            w = __expf(leaky(as1[s * 8 + hw] + adv) - m);
        }
        wsum += w;
        int cnt = min(8, deg - g * 8);
#pragma unroll
        for (int j = 0; j < 8; j++) {
            if (j >= cnt) break;
            float wj = __shfl(w, (j << 3) | ha);
            int sj = __shfl(s, (j << 3));
            const float4* xr = (const float4*)(x + (size_t)sj * 128 + cg * 16);
            float4 v0 = xr[0], v1 = xr[1], v2 = xr[2], v3 = xr[3];
            acc[0]  = fmaf(wj, v0.x, acc[0]);  acc[1]  = fmaf(wj, v0.y, acc[1]);
            acc[2]  = fmaf(wj, v0.z, acc[2]);  acc[3]  = fmaf(wj, v0.w, acc[3]);
            acc[4]  = fmaf(wj, v1.x, acc[4]);  acc[5]  = fmaf(wj, v1.y, acc[5]);
            acc[6]  = fmaf(wj, v1.z, acc[6]);  acc[7]  = fmaf(wj, v1.w, acc[7]);
            acc[8]  = fmaf(wj, v2.x, acc[8]);  acc[9]  = fmaf(wj, v2.y, acc[9]);
            acc[10] = fmaf(wj, v2.z, acc[10]); acc[11] = fmaf(wj, v2.w, acc[11]);
            acc[12] = fmaf(wj, v3.x, acc[12]); acc[13] = fmaf(wj, v3.y, acc[13]);
            acc[14] = fmaf(wj, v3.z, acc[14]); acc[15] = fmaf(wj, v3.w, acc[15]);
        }
    }
    wsum += __shfl_xor(wsum, 8);
    wsum += __shfl_xor(wsum, 16);
    wsum += __shfl_xor(wsum, 32);
    float stot = __shfl(wsum, ha);   // lane ha holds head-ha sum (e8=0, hw=ha)
    float inv = 1.0f / (stot + 1e-16f);
    unsigned int o[8];
#pragma unroll
    for (int q = 0; q < 8; q++) {
        unsigned lo = f2bf(acc[2 * q] * inv);
        unsigned hi = f2bf(acc[2 * q + 1] * inv);
        o[q] = lo | (hi << 16);
    }
    unsigned short* dst = y_b + (size_t)n * 1024 + ha * 128 + cg * 16;
    *(uint4*)(dst)     = make_uint4(o[0], o[1], o[2], o[3]);
    *(uint4*)(dst + 8) = make_uint4(o[4], o[5], o[6], o[7]);
}

// ---------------- l1_gemm (MFMA): hbuf_b = ELU(per-head y @ W1h + b1), bf16 out ----

__global__ __launch_bounds__(256) void l1_gemm(
    const unsigned short* __restrict__ y_b, const unsigned short* __restrict__ W1bT,
    const float* __restrict__ b1, unsigned short* __restrict__ hbuf_b, int N) {
    int h  = blockIdx.x & 7;
    int nb = (blockIdx.x >> 3) * 64;
    int w  = threadIdx.x >> 6;
    int lane = threadIdx.x & 63;
    int n16 = lane & 15, quad = lane >> 4;
    int node_a = nb + w * 16 + n16;
    const unsigned short* yrow =
        y_b + (size_t)(node_a < N ? node_a : 0) * 1024 + h * 128 + quad * 8;
    const unsigned short* Wh = W1bT + h * 16384 + quad * 8;
    f32x4 acc[8];
#pragma unroll
    for (int ct = 0; ct < 8; ct++) acc[ct] = (f32x4){0.f, 0.f, 0.f, 0.f};
#pragma unroll
    for (int ks = 0; ks < 4; ks++) {
        bf16x8 a = *(const bf16x8*)(yrow + ks * 32);
#pragma unroll
        for (int ct = 0; ct < 8; ct++) {
            bf16x8 b = *(const bf16x8*)(Wh + (ct * 16 + n16) * 128 + ks * 32);
            acc[ct] = __builtin_amdgcn_mfma_f32_16x16x32_bf16(a, b, acc[ct], 0, 0, 0);
        }
    }
#pragma unroll
    for (int ct = 0; ct < 8; ct++) {
        int c = h * 128 + ct * 16 + n16;
        float bias = b1[c];
#pragma unroll
        for (int r = 0; r < 4; r++) {
            int node = nb + w * 16 + quad * 4 + r;
            if (node < N) {
                float v = acc[ct][r] + bias;
                v = v > 0.f ? v : expm1f(v);
                hbuf_b[(size_t)node * 1024 + c] = f2bf(v);
            }
        }
    }
}

// ---------------- l2_transform (MFMA): h2 = hbuf @ W2, alpha_s2/ad2 -----------------

__global__ __launch_bounds__(256) void l2_transform(
    const unsigned short* __restrict__ hbuf_b, const unsigned short* __restrict__ W2bT,
    const float* __restrict__ a_src2, const float* __restrict__ a_dst2,
    float* __restrict__ h2, float* __restrict__ as2, float* __restrict__ ad2, int N) {
    int nb = blockIdx.x * 16;
    int ct = threadIdx.x >> 6;
    int lane = threadIdx.x & 63;
    int n16 = lane & 15, quad = lane >> 4;
    int node_a = nb + n16;
    const unsigned short* arow =
        hbuf_b + (size_t)(node_a < N ? node_a : N - 1) * 1024 + quad * 8;
    const unsigned short* brow = W2bT + (size_t)(ct * 16 + n16) * 1024 + quad * 8;
    f32x4 acc = (f32x4){0.f, 0.f, 0.f, 0.f};
#pragma unroll 8
    for (int ks = 0; ks < 32; ks++) {
        bf16x8 a = *(const bf16x8*)(arow + ks * 32);
        bf16x8 b = *(const bf16x8*)(brow + ks * 32);
        acc = __builtin_amdgcn_mfma_f32_16x16x32_bf16(a, b, acc, 0, 0, 0);
    }
    int c = ct * 16 + n16;
    float asc = a_src2[c], adc = a_dst2[c];
    float pav[4], pdv[4];
#pragma unroll
    for (int r = 0; r < 4; r++) {
        int node = nb + quad * 4 + r;
        if (node < N) h2[(size_t)node * 64 + c] = acc[r];
        pav[r] = acc[r] * asc;
        pdv[r] = acc[r] * adc;
#pragma unroll
        for (int mm = 1; mm <= 8; mm <<= 1) {
            pav[r] += __shfl_xor(pav[r], mm);
            pdv[r] += __shfl_xor(pdv[r], mm);
        }
    }
    __shared__ float sA[4][16], sD[4][16];
    if (n16 == 0) {
#pragma unroll
        for (int r = 0; r < 4; r++) {
            sA[ct][quad * 4 + r] = pav[r];
            sD[ct][quad * 4 + r] = pdv[r];
        }
    }
    __syncthreads();
    if (threadIdx.x < 16) {
        int node = nb + threadIdx.x;
        if (node < N) {
            as2[node] = sA[0][threadIdx.x] + sA[1][threadIdx.x] + sA[2][threadIdx.x] + sA[3][threadIdx.x];
            ad2[node] = sD[0][threadIdx.x] + sD[1][threadIdx.x] + sD[2][threadIdx.x] + sD[3][threadIdx.x];
        }
    }
}

// ---------------- l2_agg: wave-per-node, lane = output channel ----------------

__global__ __launch_bounds__(256) void l2_agg(
    const float* __restrict__ h2, const float* __restrict__ as2, const float* __restrict__ ad2,
    const float* __restrict__ b2, const int* __restrict__ offsets, const int* __restrict__ srcs,
    float* __restrict__ out, int N) {
    int n = blockIdx.x * 4 + (threadIdx.x >> 6);
    if (n >= N) return;
    int lane = threadIdx.x & 63;
    int beg = offsets[n];
    int deg = offsets[n + 1] - beg;
    float adn = ad2[n];
    float m = -3.4e38f;
    for (int i = lane; i < deg; i += 64)
        m = fmaxf(m, leaky(as2[srcs[beg + i]] + adn));
#pragma unroll
    for (int mm = 32; mm >= 1; mm >>= 1) m = fmaxf(m, __shfl_xor(m, mm));
    float acc = 0.f, wsum = 0.f;
    for (int i = 0; i < deg; i++) {
        int s = srcs[beg + i];                       // same addr all lanes
        float w = __expf(leaky(as2[s] + adn) - m);   // redundant per lane, cheap
        acc = fmaf(w, h2[(size_t)s * 64 + lane], acc);
        wsum += w;
    }
    out[(size_t)n * 64 + lane] = acc / (wsum + 1e-16f) + b2[lane];
}

// ---------------- launch ----------------

static inline size_t align_up(size_t v, size_t a) { return (v + a - 1) / a * a; }

extern "C" void kernel_launch(void* const* d_in, const int* in_sizes, int n_in,
                              void* d_out, int out_size, void* d_ws, size_t ws_size,
                              hipStream_t stream) {
    const float* x      = (const float*)d_in[0];
    const int*   ei     = (const int*)d_in[1];
    const float* W1     = (const float*)d_in[2];
    const float* a_src1 = (const float*)d_in[3];
    const float* a_dst1 = (const float*)d_in[4];
    const float* b1     = (const float*)d_in[5];
    const float* W2     = (const float*)d_in[6];
    const float* a_src2 = (const float*)d_in[7];
    const float* a_dst2 = (const float*)d_in[8];
    const float* b2     = (const float*)d_in[9];
    float* out = (float*)d_out;

    int N = in_sizes[0] / 128;
    int E = in_sizes[1] / 2;
    int M = E + N;

    char* p = (char*)d_ws;
    size_t off = 0;
    auto carve = [&](size_t bytes) {
        void* r = p + off;
        off = align_up(off + bytes, 256);
        return r;
    };
    int*            counts  = (int*)carve((size_t)N * 4);
    int*            offsets = (int*)carve((size_t)(N + 1) * 4);
    int*            cursor  = (int*)carve((size_t)N * 4);
    int*            srcs    = (int*)carve((size_t)M * 4);
    float*          As      = (float*)carve(1024 * 4);
    float*          Ad      = (float*)carve(1024 * 4);
    float*          as1     = (float*)carve((size_t)N * 8 * 4);
    float*          ad1     = (float*)carve((size_t)N * 8 * 4);
    float*          as2     = (float*)carve((size_t)N * 4);
    float*          ad2     = (float*)carve((size_t)N * 4);
    float*          h2      = (float*)carve((size_t)N * 64 * 4);
    unsigned short* W1bT    = (unsigned short*)carve((size_t)8 * 128 * 128 * 2);
    unsigned short* W2bT    = (unsigned short*)carve((size_t)64 * 1024 * 2);
    unsigned short* y_b     = (unsigned short*)carve((size_t)N * 1024 * 2);
    unsigned short* hbuf_b  = (unsigned short*)carve((size_t)N * 1024 * 2);
    (void)ws_size; // ~47 MB

    hipMemsetAsync(counts, 0, (size_t)N * 4, stream);
    prep_all<<<196, 256, 0, stream>>>(W1, a_src1, a_dst1, W2, As, Ad, W1bT, W2bT);
    alpha1_kernel<<<(N + 31) / 32, 256, 0, stream>>>(x, As, Ad, as1, ad1, N);
    count_kernel<<<(M + 255) / 256, 256, 0, stream>>>(ei, counts, E, N);
    scan_kernel<<<1, 1024, 0, stream>>>(counts, offsets, cursor, N);
    fill_kernel<<<(M + 255) / 256, 256, 0, stream>>>(ei, cursor, srcs, E, N);
    l1_aggx<<<(N + 3) / 4, 256, 0, stream>>>(x, as1, ad1, offsets, srcs, y_b, N);
    l1_gemm<<<((N + 63) / 64) * 8, 256, 0, stream>>>(y_b, W1bT, b1, hbuf_b, N);
    l2_transform<<<(N + 15) / 16, 256, 0, stream>>>(hbuf_b, W2bT, a_src2, a_dst2, h2, as2, ad2, N);
    l2_agg<<<(N + 3) / 4, 256, 0, stream>>>(h2, as2, ad2, b2, offsets, srcs, out, N);
}